// Round 1
// baseline (642.338 us; speedup 1.0000x reference)
//
#include <hip/hip_runtime.h>

// ---------------------------------------------------------------------------
// AttentionOT: q/k/v projections -> l2norm -> sim -> Sinkhorn(100it, eps=.05)
// -> score_map, x = (T @ v) @ Wp^T + bp
// Sizes: Nq=64, M=16, B=8, K=256, C=512.  All fp32 (Sinkhorn amplifies sim
// errors by 1/eps=20x, so no bf16 on the front path this round).
// ---------------------------------------------------------------------------

#define BM 128
#define BN 128
#define BKD 16

static __device__ __forceinline__ float fastrcp(float x) {
    return __builtin_amdgcn_rcpf(x);
}

// Generic 128x128 tiled fp32 GEMM:  Out[i,j] = sum_t A(i,t) * B(j,t) (+bias)
//  A_KM: A stored k-major  A[t*lda + i]   else row-major A[i*lda + t]
//  B_KM: B stored k-major  B[t*ldb + j]   else row-major B[j*ldb + t]
//  OPERM: output row remap (b*1024+m*64+n) -> (n*128+m*8+b)  (xpre -> x)
// blockIdx.z batches with element strides sAb/sBb/sOb.
// All dims must be multiples of the tile sizes (true for every call here).
template <bool A_KM, bool B_KM, bool BIAS, bool OPERM>
__global__ __launch_bounds__(256) void gemm_tile(
    const float* __restrict__ A, const float* __restrict__ B,
    const float* __restrict__ bias, float* __restrict__ Out,
    int Kdim, int lda, int ldb, int ldo,
    long sAb, long sBb, long sOb)
{
    A   += (long)blockIdx.z * sAb;
    B   += (long)blockIdx.z * sBb;
    Out += (long)blockIdx.z * sOb;

    __shared__ float As[BKD][BM + 4];
    __shared__ float Bs[BKD][BN + 4];

    const int tid = threadIdx.x;
    const int i0 = blockIdx.x * BM;
    const int j0 = blockIdx.y * BN;
    const int tx = tid & 15;        // 16 cols of threads
    const int ty = tid >> 4;        // 16 rows of threads

    float acc[8][8];
#pragma unroll
    for (int a = 0; a < 8; a++)
#pragma unroll
        for (int b = 0; b < 8; b++) acc[a][b] = 0.0f;

    for (int k0 = 0; k0 < Kdim; k0 += BKD) {
        // ---- stage A tile ----
        if constexpr (A_KM) {
            const int t  = tid >> 5;            // 0..7
            const int i4 = (tid & 31) << 2;     // 0..124
#pragma unroll
            for (int rep = 0; rep < 2; rep++) {
                float4 v = *(const float4*)(A + (long)(k0 + t + rep * 8) * lda + (i0 + i4));
                *(float4*)&As[t + rep * 8][i4] = v;
            }
        } else {
            const int r  = tid >> 2;            // 0..63
            const int kq = (tid & 3) << 2;      // 0,4,8,12
#pragma unroll
            for (int rep = 0; rep < 2; rep++) {
                float4 v = *(const float4*)(A + (long)(i0 + r + rep * 64) * lda + (k0 + kq));
                As[kq + 0][r + rep * 64] = v.x;
                As[kq + 1][r + rep * 64] = v.y;
                As[kq + 2][r + rep * 64] = v.z;
                As[kq + 3][r + rep * 64] = v.w;
            }
        }
        // ---- stage B tile ----
        if constexpr (B_KM) {
            const int t  = tid >> 5;
            const int j4 = (tid & 31) << 2;
#pragma unroll
            for (int rep = 0; rep < 2; rep++) {
                float4 v = *(const float4*)(B + (long)(k0 + t + rep * 8) * ldb + (j0 + j4));
                *(float4*)&Bs[t + rep * 8][j4] = v;
            }
        } else {
            const int r  = tid >> 2;
            const int kq = (tid & 3) << 2;
#pragma unroll
            for (int rep = 0; rep < 2; rep++) {
                float4 v = *(const float4*)(B + (long)(j0 + r + rep * 64) * ldb + (k0 + kq));
                Bs[kq + 0][r + rep * 64] = v.x;
                Bs[kq + 1][r + rep * 64] = v.y;
                Bs[kq + 2][r + rep * 64] = v.z;
                Bs[kq + 3][r + rep * 64] = v.w;
            }
        }
        __syncthreads();

        // ---- 8x8 micro-tile: rows {ty*4..+3, 64+ty*4..+3}, cols likewise ----
#pragma unroll
        for (int kk = 0; kk < BKD; kk++) {
            float a[8], b[8];
            *(float4*)&a[0] = *(const float4*)&As[kk][ty * 4];
            *(float4*)&a[4] = *(const float4*)&As[kk][64 + ty * 4];
            *(float4*)&b[0] = *(const float4*)&Bs[kk][tx * 4];
            *(float4*)&b[4] = *(const float4*)&Bs[kk][64 + tx * 4];
#pragma unroll
            for (int ii = 0; ii < 8; ii++)
#pragma unroll
                for (int jj = 0; jj < 8; jj++)
                    acc[ii][jj] = fmaf(a[ii], b[jj], acc[ii][jj]);
        }
        __syncthreads();
    }

    // ---- epilogue ----
    float4 bv0 = {0, 0, 0, 0}, bv1 = {0, 0, 0, 0};
    if constexpr (BIAS) {
        bv0 = *(const float4*)(bias + j0 + tx * 4);
        bv1 = *(const float4*)(bias + j0 + 64 + tx * 4);
    }
#pragma unroll
    for (int half = 0; half < 2; half++) {
#pragma unroll
        for (int rr = 0; rr < 4; rr++) {
            const int i = i0 + half * 64 + ty * 4 + rr;
            long orow;
            if constexpr (OPERM) {
                const int n = i & 63, m = (i >> 6) & 15, bb = i >> 10;
                orow = (long)(n * 128 + m * 8 + bb);
            } else {
                orow = i;
            }
            const int ii = half * 4 + rr;
            float4 v0, v1;
            v0.x = acc[ii][0]; v0.y = acc[ii][1]; v0.z = acc[ii][2]; v0.w = acc[ii][3];
            v1.x = acc[ii][4]; v1.y = acc[ii][5]; v1.z = acc[ii][6]; v1.w = acc[ii][7];
            if constexpr (BIAS) {
                v0.x += bv0.x; v0.y += bv0.y; v0.z += bv0.z; v0.w += bv0.w;
                v1.x += bv1.x; v1.y += bv1.y; v1.z += bv1.z; v1.w += bv1.w;
            }
            *(float4*)(Out + orow * ldo + j0 + tx * 4)      = v0;
            *(float4*)(Out + orow * ldo + j0 + 64 + tx * 4) = v1;
        }
    }
}

// Per-row L2 normalize (512 floats/row), one wave per row.
// PERM: write q rows permuted from (n*16+m)*8+b  ->  b*1024 + m*64 + n
template <bool PERM>
__global__ __launch_bounds__(256) void l2norm_kernel(
    const float* __restrict__ src, float* __restrict__ dst)
{
    const int row  = blockIdx.x * 4 + (threadIdx.x >> 6);
    const int lane = threadIdx.x & 63;
    const float* s = src + (long)row * 512 + lane * 8;
    float4 x0 = *(const float4*)s;
    float4 x1 = *(const float4*)(s + 4);
    float ss = x0.x * x0.x + x0.y * x0.y + x0.z * x0.z + x0.w * x0.w
             + x1.x * x1.x + x1.y * x1.y + x1.z * x1.z + x1.w * x1.w;
#pragma unroll
    for (int off = 32; off; off >>= 1) ss += __shfl_xor(ss, off, 64);
    const float scale = 1.0f / fmaxf(sqrtf(ss), 1e-12f);
    long drow;
    if constexpr (PERM) {
        const int b = row & 7, m = (row >> 3) & 15, n = row >> 7;
        drow = (long)b * 1024 + m * 64 + n;
    } else {
        drow = row;
    }
    float* d = dst + drow * 512 + lane * 8;
    x0.x *= scale; x0.y *= scale; x0.z *= scale; x0.w *= scale;
    x1.x *= scale; x1.y *= scale; x1.z *= scale; x1.w *= scale;
    *(float4*)d       = x0;
    *(float4*)(d + 4) = x1;
}

// Sinkhorn, multiplicative form (exactly equivalent to the reference's
// log-domain update with a=exp(u/eps), b=exp(v/eps); values provably stay
// in fp32 range: kern in [-26, -2.7]).  One wave per (b,k) problem; lane=n.
//   K[m,n] = exp((sim-1)/eps);  a_m = mu'/sum_n K b;  b_n = nu'/sum_m K a
// 100 iterations, then T = a*K*b, score = 1024*sim*T.
// T may alias sim (sim is fully register-resident before any store).
__global__ __launch_bounds__(256) void sinkhorn_kernel(
    const float* __restrict__ sim, float* __restrict__ T,
    float* __restrict__ score)
{
    const int lane = threadIdx.x & 63;
    const int bk   = blockIdx.x * 4 + (threadIdx.x >> 6);
    const float* S = sim + (long)bk * 1024;

    float Kv[16], sv[16];
#pragma unroll
    for (int m = 0; m < 16; m++) {
        sv[m] = S[m * 64 + lane];
        Kv[m] = __expf((sv[m] - 1.0f) * 20.0f);   // 1/eps = 20
    }

    const float muP = 1.0f / 16.0f + 1e-8f;   // exp(log(mu + 1e-8))
    const float nuP = 1.0f / 64.0f + 1e-8f;
    float b = 1.0f;
    float am[16];

#pragma unroll 1
    for (int it = 0; it < 100; it++) {
        // u-step: S_m = sum_n K[m,n] * b[n]   (16 wave-wide reductions)
        float s[16];
#pragma unroll
        for (int m = 0; m < 16; m++) s[m] = Kv[m] * b;
#pragma unroll
        for (int off = 32; off; off >>= 1) {
#pragma unroll
            for (int m = 0; m < 16; m++) s[m] += __shfl_xor(s[m], off, 64);
        }
#pragma unroll
        for (int m = 0; m < 16; m++) am[m] = muP * fastrcp(s[m]);
        // v-step: S'_n = sum_m K[m,n] * a[m]   (lane-local)
        float t = 0.0f;
#pragma unroll
        for (int m = 0; m < 16; m++) t = fmaf(Kv[m], am[m], t);
        b = nuP * fastrcp(t);
    }

#pragma unroll
    for (int m = 0; m < 16; m++) {
        const float Tv = am[m] * Kv[m] * b;
        T[(long)bk * 1024 + m * 64 + lane]     = Tv;
        score[(long)bk * 1024 + m * 64 + lane] = 1024.0f * sv[m] * Tv;
    }
}

extern "C" void kernel_launch(void* const* d_in, const int* in_sizes, int n_in,
                              void* d_out, int out_size, void* d_ws, size_t ws_size,
                              hipStream_t stream)
{
    (void)in_sizes; (void)n_in; (void)out_size; (void)ws_size;
    const float* xq = (const float*)d_in[0];
    const float* xk = (const float*)d_in[1];
    const float* xv = (const float*)d_in[2];
    const float* Wq = (const float*)d_in[3];
    const float* Wk = (const float*)d_in[4];
    const float* Wv = (const float*)d_in[5];
    const float* Wp = (const float*)d_in[6];
    const float* bp = (const float*)d_in[7];

    float* out_x     = (float*)d_out;            // (Nq,M,B,C) = 8192 x 512
    float* out_score = out_x + 8192L * 512;      // (B,K,M,Nq) = 2048 x 1024

    // workspace layout (floats); total 12,582,912 floats = 48 MB
    float* ws    = (float*)d_ws;
    float* qraw  = ws;              // 8192x512 (reused as xpre after normalize)
    float* qperm = ws + 4194304;    // 8192x512, layout [b][m*64+n][c]
    float* kbuf  = ws + 8388608;    // 2048x512, [b][k][c] (normalized in place)
    float* vbuf  = ws + 9437184;    // 2048x512
    float* simT  = ws + 10485760;   // 2048x1024: sim, overwritten in-place by T

    const dim3 blk(256);

    // 1-3: projections (Out = X @ W^T)
    gemm_tile<false, false, false, false><<<dim3(64, 4, 1), blk, 0, stream>>>(
        xq, Wq, nullptr, qraw, 512, 512, 512, 512, 0, 0, 0);
    gemm_tile<false, false, false, false><<<dim3(16, 4, 1), blk, 0, stream>>>(
        xk, Wk, nullptr, kbuf, 512, 512, 512, 512, 0, 0, 0);
    gemm_tile<false, false, false, false><<<dim3(16, 4, 1), blk, 0, stream>>>(
        xv, Wv, nullptr, vbuf, 512, 512, 512, 512, 0, 0, 0);

    // 4: l2 normalize q (with permute to [b][mn][c]) and k (in place)
    l2norm_kernel<true ><<<2048, blk, 0, stream>>>(qraw, qperm);
    l2norm_kernel<false><<< 512, blk, 0, stream>>>(kbuf, kbuf);

    // 5: sim[b][k][mn] = kk_b @ qperm_b^T   (batched over b via blockIdx.z)
    gemm_tile<false, false, false, false><<<dim3(2, 8, 8), blk, 0, stream>>>(
        kbuf, qperm, nullptr, simT, 512, 512, 512, 1024,
        131072, 524288, 262144);

    // 6: Sinkhorn (T overwrites sim; score straight to output)
    sinkhorn_kernel<<<512, blk, 0, stream>>>(simT, simT, out_score);

    // 7: xpre[b][mn][c] = sum_k T_b[k,mn] * V_b[k,c]   (both operands k-major)
    gemm_tile<true, true, false, false><<<dim3(8, 4, 8), blk, 0, stream>>>(
        simT, vbuf, nullptr, qraw, 256, 1024, 512, 512,
        262144, 131072, 524288);

    // 8: x = xpre @ Wp^T + bp, rows permuted (b,mn) -> (n,m,b)
    gemm_tile<false, false, true, true><<<dim3(64, 4, 1), blk, 0, stream>>>(
        qraw, Wp, bp, out_x, 512, 512, 512, 512, 0, 0, 0);
}

// Round 2
// 314.993 us; speedup vs baseline: 2.0392x; 2.0392x over previous
//
#include <hip/hip_runtime.h>

// ---------------------------------------------------------------------------
// AttentionOT  (Nq=64, M=16, B=8, K=256, C=512)
//   fp32 path (error-critical, feeds exp(20*sim)): q/k proj, l2norm, sim
//   bf16 MFMA path (error-tolerant):               v proj, T@V, final proj
//   Sinkhorn: dual-layout multiplicative form, 7 DS ops/iter (was 96)
// ---------------------------------------------------------------------------

typedef short   short8  __attribute__((ext_vector_type(8)));
typedef float   floatx4 __attribute__((ext_vector_type(4)));

static __device__ __forceinline__ float fastrcp(float x) {
    return __builtin_amdgcn_rcpf(x);
}
static __device__ __forceinline__ unsigned short f2bf(float f) {
    union { float f; unsigned u; } c; c.f = f;
    unsigned r = c.u + 0x7FFF + ((c.u >> 16) & 1);   // RNE
    return (unsigned short)(r >> 16);
}
static __device__ __forceinline__ float bcast(float v, int l) {
    return __int_as_float(__builtin_amdgcn_readlane(__float_as_int(v), l));
}

// ---------------------------------------------------------------------------
// fp32 GEMM, 64x64 tile, 4x4 micro-tile, BK=16.  Out[i,j] = sum_t A[i,t]B[j,t]
// Grid: (rows/64, cols/64, batch); 256 threads.  ~40 VGPR -> 16 waves/CU at
// 4 blocks/CU (the round-1 128-tile gave k/v-proj and sim only <=1 block/CU).
// ---------------------------------------------------------------------------
__global__ __launch_bounds__(256) void gemm_f32_64(
    const float* __restrict__ A, const float* __restrict__ B,
    float* __restrict__ Out, int Kdim, int lda, int ldb, int ldo,
    long sA, long sB, long sO)
{
    A   += (long)blockIdx.z * sA;
    B   += (long)blockIdx.z * sB;
    Out += (long)blockIdx.z * sO;

    __shared__ float As[16][68];
    __shared__ float Bs[16][68];

    const int tid = threadIdx.x;
    const int tx = tid & 15, ty = tid >> 4;
    const int i0 = blockIdx.x * 64, j0 = blockIdx.y * 64;
    const int sr = tid >> 2, skq = (tid & 3) << 2;

    float acc[4][4];
#pragma unroll
    for (int a = 0; a < 4; a++)
#pragma unroll
        for (int b = 0; b < 4; b++) acc[a][b] = 0.0f;

    for (int k0 = 0; k0 < Kdim; k0 += 16) {
        float4 va = *(const float4*)(A + (long)(i0 + sr) * lda + k0 + skq);
        float4 vb = *(const float4*)(B + (long)(j0 + sr) * ldb + k0 + skq);
        As[skq + 0][sr] = va.x; As[skq + 1][sr] = va.y;
        As[skq + 2][sr] = va.z; As[skq + 3][sr] = va.w;
        Bs[skq + 0][sr] = vb.x; Bs[skq + 1][sr] = vb.y;
        Bs[skq + 2][sr] = vb.z; Bs[skq + 3][sr] = vb.w;
        __syncthreads();
#pragma unroll
        for (int kk = 0; kk < 16; kk++) {
            float4 a = *(const float4*)&As[kk][ty * 4];
            float4 b = *(const float4*)&Bs[kk][tx * 4];
            const float ar[4] = {a.x, a.y, a.z, a.w};
            const float br[4] = {b.x, b.y, b.z, b.w};
#pragma unroll
            for (int ii = 0; ii < 4; ii++)
#pragma unroll
                for (int jj = 0; jj < 4; jj++)
                    acc[ii][jj] = fmaf(ar[ii], br[jj], acc[ii][jj]);
        }
        __syncthreads();
    }
#pragma unroll
    for (int rr = 0; rr < 4; rr++) {
        float4 o;
        o.x = acc[rr][0]; o.y = acc[rr][1]; o.z = acc[rr][2]; o.w = acc[rr][3];
        *(float4*)(Out + (long)(i0 + ty * 4 + rr) * ldo + j0 + tx * 4) = o;
    }
}

// ---------------------------------------------------------------------------
// bf16 MFMA GEMM, 128x128 tile, BK=32, 4 waves each computing a 64x64
// quadrant as 4x4 tiles of 16x16x32 MFMA (m97-style; frag layouts per
// learn_hip m89: A lane l -> A[m=l&15][k=(l>>4)*8+j]; C/D col=l&15,
// row=(l>>4)*4+reg).  Operands stored [row][k] / [col][k], bf16 bits in short.
//  OTRANS: write Out transposed per-batch-of-256 rows: vt[b][c][k']
//  OPERM : row (b*1024+m*64+n) -> (n*128+m*8+b)
// ---------------------------------------------------------------------------
template <bool OTRANS, bool BIAS, bool OPERM, bool OUT_BF16>
__global__ __launch_bounds__(256) void gemm_bf16(
    const short* __restrict__ A, const short* __restrict__ B,
    const float* __restrict__ bias, void* __restrict__ OutV,
    int Kdim, int lda, int ldb, int ldo, long sA, long sB, long sO)
{
    A += (long)blockIdx.z * sA;
    B += (long)blockIdx.z * sB;

    __shared__ __align__(16) short As[128][40];   // pad: 80B stride, 2-way max
    __shared__ __align__(16) short Bs[128][40];

    const int tid  = threadIdx.x;
    const int lane = tid & 63;
    const int wv   = tid >> 6;
    const int wr   = (wv >> 1) * 64;
    const int wc   = (wv & 1) * 64;
    const int i0 = blockIdx.x * 128, j0 = blockIdx.y * 128;

    floatx4 acc[4][4];
#pragma unroll
    for (int i = 0; i < 4; i++)
#pragma unroll
        for (int j = 0; j < 4; j++) acc[i][j] = {0.f, 0.f, 0.f, 0.f};

    const int srow = tid >> 2;
    const int sch  = (tid & 3) * 8;
    const int fr = lane & 15, fq = (lane >> 4) * 8;

    for (int k0 = 0; k0 < Kdim; k0 += 32) {
#pragma unroll
        for (int p = 0; p < 2; p++) {
            const int r = srow + p * 64;
            *(short8*)&As[r][sch] = *(const short8*)(A + (long)(i0 + r) * lda + k0 + sch);
            *(short8*)&Bs[r][sch] = *(const short8*)(B + (long)(j0 + r) * ldb + k0 + sch);
        }
        __syncthreads();
        short8 af[4], bf[4];
#pragma unroll
        for (int i = 0; i < 4; i++) af[i] = *(const short8*)&As[wr + i * 16 + fr][fq];
#pragma unroll
        for (int j = 0; j < 4; j++) bf[j] = *(const short8*)&Bs[wc + j * 16 + fr][fq];
#pragma unroll
        for (int i = 0; i < 4; i++)
#pragma unroll
            for (int j = 0; j < 4; j++)
                acc[i][j] = __builtin_amdgcn_mfma_f32_16x16x32_bf16(
                    af[i], bf[j], acc[i][j], 0, 0, 0);
        __syncthreads();
    }

    float* Of = nullptr; unsigned short* Ob = nullptr;
    if constexpr (OUT_BF16) Ob = (unsigned short*)OutV + (long)blockIdx.z * sO;
    else                    Of = (float*)OutV + (long)blockIdx.z * sO;
    const int cr = (lane >> 4) * 4, cc = lane & 15;
#pragma unroll
    for (int i = 0; i < 4; i++) {
#pragma unroll
        for (int j = 0; j < 4; j++) {
            const int gj = j0 + wc + j * 16 + cc;
            float bb = 0.0f;
            if constexpr (BIAS) bb = bias[gj];
#pragma unroll
            for (int r = 0; r < 4; r++) {
                const int gi = i0 + wr + i * 16 + cr + r;
                float v = acc[i][j][r] + bb;
                long idx;
                if constexpr (OTRANS)
                    idx = (long)(gi >> 8) * 131072 + (long)gj * 256 + (gi & 255);
                else if constexpr (OPERM)
                    idx = (long)((gi & 63) * 128 + ((gi >> 6) & 15) * 8 + (gi >> 10)) * ldo + gj;
                else
                    idx = (long)gi * ldo + gj;
                if constexpr (OUT_BF16) Ob[idx] = f2bf(v);
                else                    Of[idx] = v;
            }
        }
    }
}

// ---------------------------------------------------------------------------
// Per-row L2 normalize (512 floats), one wave per row.
// PERM: q rows (n*16+m)*8+b -> b*1024 + m*64 + n
// ---------------------------------------------------------------------------
template <bool PERM>
__global__ __launch_bounds__(256) void l2norm_kernel(
    const float* __restrict__ src, float* __restrict__ dst)
{
    const int row  = blockIdx.x * 4 + (threadIdx.x >> 6);
    const int lane = threadIdx.x & 63;
    const float* s = src + (long)row * 512 + lane * 8;
    float4 x0 = *(const float4*)s;
    float4 x1 = *(const float4*)(s + 4);
    float ss = x0.x * x0.x + x0.y * x0.y + x0.z * x0.z + x0.w * x0.w
             + x1.x * x1.x + x1.y * x1.y + x1.z * x1.z + x1.w * x1.w;
#pragma unroll
    for (int off = 32; off; off >>= 1) ss += __shfl_xor(ss, off, 64);
    const float scale = 1.0f / fmaxf(sqrtf(ss), 1e-12f);
    long drow;
    if constexpr (PERM) {
        const int b = row & 7, m = (row >> 3) & 15, n = row >> 7;
        drow = (long)b * 1024 + m * 64 + n;
    } else {
        drow = row;
    }
    float* d = dst + drow * 512 + lane * 8;
    x0.x *= scale; x0.y *= scale; x0.z *= scale; x0.w *= scale;
    x1.x *= scale; x1.y *= scale; x1.z *= scale; x1.w *= scale;
    *(float4*)d       = x0;
    *(float4*)(d + 4) = x1;
}

// ---------------------------------------------------------------------------
// Sinkhorn, multiplicative form (== reference log-domain update with
// a=exp(u/eps), b=exp(v/eps); kern in [-80,0] -> all fp32-safe).
// Dual layout kills the 96-shuffle/iter bottleneck of round 1:
//   K1: lane l=(m|16nc) holds K[m][16nc..16nc+15]  (u-step: 16 fma + 2 shfl)
//   K2: lane l=n holds K[0..15][n]                 (v-step: 16 fma, a_m via
//       v_readlane -> SGPR, zero DS ops)
//   b -> bB redistribution: 1 ds_write + 4 ds_read_b128 per iteration.
// Outputs: score (fp32, to d_out) and T as bf16 in [b][mn][k'] for the T@V
// MFMA GEMM.
// ---------------------------------------------------------------------------
__global__ __launch_bounds__(256) void sinkhorn2(
    const float* __restrict__ sim, float* __restrict__ score,
    unsigned short* __restrict__ Tt)
{
    __shared__ float lb[4][64];
    const int lane = threadIdx.x & 63;
    const int wv   = threadIdx.x >> 6;
    const int bk   = blockIdx.x * 4 + wv;
    const float* S = sim + (long)bk * 1024;

    float sv[16], K2[16];
#pragma unroll
    for (int m = 0; m < 16; m++) {
        sv[m] = S[m * 64 + lane];
        K2[m] = __expf((sv[m] - 1.0f) * 20.0f);
    }
    const int mB = lane & 15, nc = lane >> 4;
    float K1[16];
#pragma unroll
    for (int c4 = 0; c4 < 4; c4++) {
        float4 v = *(const float4*)(S + mB * 64 + nc * 16 + c4 * 4);
        K1[c4 * 4 + 0] = __expf((v.x - 1.0f) * 20.0f);
        K1[c4 * 4 + 1] = __expf((v.y - 1.0f) * 20.0f);
        K1[c4 * 4 + 2] = __expf((v.z - 1.0f) * 20.0f);
        K1[c4 * 4 + 3] = __expf((v.w - 1.0f) * 20.0f);
    }

    const float muP = 0.0625f + 1e-8f;     // exp(log(mu + 1e-8))
    const float nuP = 0.015625f + 1e-8f;
    float b = 1.0f, a = 0.0f;
    float bB[16];
#pragma unroll
    for (int j = 0; j < 16; j++) bB[j] = 1.0f;

#pragma unroll 1
    for (int it = 0; it < 100; it++) {
        // u-step (layout B): s_m = sum_n K[m,n] b_n
        float s0 = 0, s1 = 0, s2 = 0, s3 = 0;
#pragma unroll
        for (int j = 0; j < 4; j++) {
            s0 = fmaf(K1[j],      bB[j],      s0);
            s1 = fmaf(K1[4 + j],  bB[4 + j],  s1);
            s2 = fmaf(K1[8 + j],  bB[8 + j],  s2);
            s3 = fmaf(K1[12 + j], bB[12 + j], s3);
        }
        float s = (s0 + s1) + (s2 + s3);
        s += __shfl_xor(s, 16, 64);
        s += __shfl_xor(s, 32, 64);
        a = muP * fastrcp(s);
        // v-step (layout O): t_n = sum_m K[m,n] a_m  (a_m as SGPRs)
        float t0 = 0, t1 = 0, t2 = 0, t3 = 0;
#pragma unroll
        for (int m = 0; m < 4; m++) {
            t0 = fmaf(K2[m],      bcast(a, m),      t0);
            t1 = fmaf(K2[4 + m],  bcast(a, 4 + m),  t1);
            t2 = fmaf(K2[8 + m],  bcast(a, 8 + m),  t2);
            t3 = fmaf(K2[12 + m], bcast(a, 12 + m), t3);
        }
        b = nuP * fastrcp((t0 + t1) + (t2 + t3));
        // redistribute b (lane=n) -> bB (lane=(m|16nc) needs b[16nc..+15])
        lb[wv][lane] = b;
        const float* p = &lb[wv][nc * 16];
        float4 q0 = *(const float4*)(p + 0);
        float4 q1 = *(const float4*)(p + 4);
        float4 q2 = *(const float4*)(p + 8);
        float4 q3 = *(const float4*)(p + 12);
        bB[0] = q0.x; bB[1] = q0.y; bB[2]  = q0.z; bB[3]  = q0.w;
        bB[4] = q1.x; bB[5] = q1.y; bB[6]  = q1.z; bB[7]  = q1.w;
        bB[8] = q2.x; bB[9] = q2.y; bB[10] = q2.z; bB[11] = q2.w;
        bB[12] = q3.x; bB[13] = q3.y; bB[14] = q3.z; bB[15] = q3.w;
    }

    const long tb = (long)(bk >> 8) * 262144 + (bk & 255);
#pragma unroll
    for (int m = 0; m < 16; m++) {
        const float Tv = bcast(a, m) * K2[m] * b;
        score[(long)bk * 1024 + m * 64 + lane] = 1024.0f * sv[m] * Tv;
        Tt[tb + (long)(m * 64 + lane) * 256] = f2bf(Tv);
    }
}

__global__ __launch_bounds__(256) void cast_bf16(
    const float* __restrict__ src, unsigned short* __restrict__ dst, int n4)
{
    const int i = blockIdx.x * 256 + threadIdx.x;
    if (i < n4) {
        float4 v = ((const float4*)src)[i];
        ushort4 o;
        o.x = f2bf(v.x); o.y = f2bf(v.y); o.z = f2bf(v.z); o.w = f2bf(v.w);
        ((ushort4*)dst)[i] = o;
    }
}

extern "C" void kernel_launch(void* const* d_in, const int* in_sizes, int n_in,
                              void* d_out, int out_size, void* d_ws, size_t ws_size,
                              hipStream_t stream)
{
    (void)in_sizes; (void)n_in; (void)out_size; (void)ws_size;
    const float* xq = (const float*)d_in[0];
    const float* xk = (const float*)d_in[1];
    const float* xv = (const float*)d_in[2];
    const float* Wq = (const float*)d_in[3];
    const float* Wk = (const float*)d_in[4];
    const float* Wv = (const float*)d_in[5];
    const float* Wp = (const float*)d_in[6];
    const float* bp = (const float*)d_in[7];

    float* out_x     = (float*)d_out;           // (Nq,M,B,C) = 8192 x 512
    float* out_score = out_x + 8192L * 512;     // (B,K,M,Nq) = 2048 x 1024

    // workspace (45 MB used; 48 MB proven available in round 1)
    char* W = (char*)d_ws;
    const long MB = 1 << 20;
    float*          qraw   = (float*)(W + 0);            // 16MB, dead after l2norm
    float*          simbuf = (float*)(W + 0);            //  8MB (reuses qraw)
    unsigned short* xpre   = (unsigned short*)(W + 8 * MB);   // 8MB bf16
    float*          qperm  = (float*)(W + 16 * MB);      // 16MB
    float*          kbuf   = (float*)(W + 32 * MB);      //  4MB
    unsigned short* xv_bf  = (unsigned short*)(W + 36 * MB);  // 2MB
    unsigned short* vt     = (unsigned short*)(W + 38 * MB);  // 2MB [b][c][k']
    unsigned short* Tt     = (unsigned short*)(W + 40 * MB);  // 4MB [b][mn][k']
    unsigned short* Wv_bf  = (unsigned short*)(W + 44 * MB);
    unsigned short* Wp_bf  = (unsigned short*)(W + 44 * MB + 524288);

    const dim3 blk(256);

    cast_bf16<<<1024, blk, 0, stream>>>(xv, xv_bf, 262144);
    cast_bf16<<< 256, blk, 0, stream>>>(Wv, Wv_bf, 65536);
    cast_bf16<<< 256, blk, 0, stream>>>(Wp, Wp_bf, 65536);

    // q/k projections (fp32: feed l2norm -> sim -> exp(20*sim))
    gemm_f32_64<<<dim3(128, 8, 1), blk, 0, stream>>>(
        xq, Wq, qraw, 512, 512, 512, 512, 0, 0, 0);
    gemm_f32_64<<<dim3(32, 8, 1), blk, 0, stream>>>(
        xk, Wk, kbuf, 512, 512, 512, 512, 0, 0, 0);

    l2norm_kernel<true ><<<2048, blk, 0, stream>>>(qraw, qperm);
    l2norm_kernel<false><<< 512, blk, 0, stream>>>(kbuf, kbuf);

    // v projection (bf16 MFMA), output transposed to vt[b][c][k']
    gemm_bf16<true, false, false, true><<<dim3(16, 4, 1), blk, 0, stream>>>(
        (const short*)xv_bf, (const short*)Wv_bf, nullptr, vt,
        512, 512, 512, 0, 0, 0, 0);

    // sim[b][k'][mn] (fp32)
    gemm_f32_64<<<dim3(4, 16, 8), blk, 0, stream>>>(
        kbuf, qperm, simbuf, 512, 512, 512, 1024, 131072, 524288, 262144);

    // Sinkhorn -> score (out) + T bf16 [b][mn][k']
    sinkhorn2<<<512, blk, 0, stream>>>(simbuf, out_score, Tt);

    // xpre[b][mn][c] = sum_k' T[b][mn][k'] * v[b][k'][c]   (bf16 MFMA)
    gemm_bf16<false, false, false, true><<<dim3(8, 4, 8), blk, 0, stream>>>(
        (const short*)Tt, (const short*)vt, nullptr, xpre,
        256, 256, 256, 512, 262144, 131072, 524288);

    // x = xpre @ Wp^T + bp, rows (b,mn)->(n,m,b)  (bf16 MFMA, fp32 out)
    gemm_bf16<false, true, true, false><<<dim3(64, 4, 1), blk, 0, stream>>>(
        (const short*)xpre, (const short*)Wp_bf, bp, out_x,
        512, 512, 512, 512, 0, 0, 0);
}

// Round 3
// 267.725 us; speedup vs baseline: 2.3992x; 1.1766x over previous
//
#include <hip/hip_runtime.h>

// ---------------------------------------------------------------------------
// AttentionOT  (Nq=64, M=16, B=8, K=256, C=512)
//   Front path (error-critical, feeds exp(20*sim)): bf16x3 split MFMA
//     (Markidis): A*B ~= Ah*Bh + Ah*Bl + Al*Bh, fp32 accumulate -> ~fp32
//     precision at MFMA rate (replaces round-2's LDS-bound fp32 vector GEMM
//     that ran at 61 TF / 39% of vector peak).
//   Back half (error-tolerant): plain bf16 MFMA.
//   Sinkhorn: dual-layout multiplicative form (round-2 kernel, unchanged).
// ---------------------------------------------------------------------------

typedef short   short8  __attribute__((ext_vector_type(8)));
typedef float   floatx4 __attribute__((ext_vector_type(4)));

static __device__ __forceinline__ float fastrcp(float x) {
    return __builtin_amdgcn_rcpf(x);
}
static __device__ __forceinline__ unsigned short f2bf(float f) {
    union { float f; unsigned u; } c; c.f = f;
    unsigned r = c.u + 0x7FFF + ((c.u >> 16) & 1);   // RNE
    return (unsigned short)(r >> 16);
}
static __device__ __forceinline__ float bf2f(unsigned short h) {
    union { unsigned u; float f; } c; c.u = (unsigned)h << 16;
    return c.f;
}
static __device__ __forceinline__ float bcast(float v, int l) {
    return __int_as_float(__builtin_amdgcn_readlane(__float_as_int(v), l));
}

// ---------------------------------------------------------------------------
// bf16x3 split GEMM: Out[i,j] = sum_t A[i,t]*B[j,t] in ~fp32 precision.
// 128x128 tile, BK=32, 4 waves in 2x2, each 4x4 of 16x16x32 MFMA, 3 MFMA
// per (i,j,k) (hh, hl, lh).  Operands row-major [row][K] bf16 (hi/lo pairs).
// ---------------------------------------------------------------------------
__global__ __launch_bounds__(256) void gemm_split3(
    const short* __restrict__ Ah, const short* __restrict__ Al,
    const short* __restrict__ Bh, const short* __restrict__ Bl,
    float* __restrict__ Out, int Kdim, int lda, int ldb, int ldo,
    long sA, long sB, long sO)
{
    Ah += (long)blockIdx.z * sA;  Al += (long)blockIdx.z * sA;
    Bh += (long)blockIdx.z * sB;  Bl += (long)blockIdx.z * sB;
    Out += (long)blockIdx.z * sO;

    __shared__ __align__(16) short Ash[128][40];
    __shared__ __align__(16) short Asl[128][40];
    __shared__ __align__(16) short Bsh[128][40];
    __shared__ __align__(16) short Bsl[128][40];

    const int tid  = threadIdx.x;
    const int lane = tid & 63;
    const int wv   = tid >> 6;
    const int wr   = (wv >> 1) * 64;
    const int wc   = (wv & 1) * 64;
    const int i0 = blockIdx.x * 128, j0 = blockIdx.y * 128;

    floatx4 acc[4][4];
#pragma unroll
    for (int i = 0; i < 4; i++)
#pragma unroll
        for (int j = 0; j < 4; j++) acc[i][j] = {0.f, 0.f, 0.f, 0.f};

    const int srow = tid >> 2;
    const int sch  = (tid & 3) * 8;
    const int fr = lane & 15, fq = (lane >> 4) * 8;

    for (int k0 = 0; k0 < Kdim; k0 += 32) {
#pragma unroll
        for (int p = 0; p < 2; p++) {
            const int r = srow + p * 64;
            const long ao = (long)(i0 + r) * lda + k0 + sch;
            const long bo = (long)(j0 + r) * ldb + k0 + sch;
            *(short8*)&Ash[r][sch] = *(const short8*)(Ah + ao);
            *(short8*)&Asl[r][sch] = *(const short8*)(Al + ao);
            *(short8*)&Bsh[r][sch] = *(const short8*)(Bh + bo);
            *(short8*)&Bsl[r][sch] = *(const short8*)(Bl + bo);
        }
        __syncthreads();
        short8 ah[4], al[4], bh[4], bl[4];
#pragma unroll
        for (int i = 0; i < 4; i++) {
            ah[i] = *(const short8*)&Ash[wr + i * 16 + fr][fq];
            al[i] = *(const short8*)&Asl[wr + i * 16 + fr][fq];
        }
#pragma unroll
        for (int j = 0; j < 4; j++) {
            bh[j] = *(const short8*)&Bsh[wc + j * 16 + fr][fq];
            bl[j] = *(const short8*)&Bsl[wc + j * 16 + fr][fq];
        }
#pragma unroll
        for (int i = 0; i < 4; i++)
#pragma unroll
            for (int j = 0; j < 4; j++) {
                acc[i][j] = __builtin_amdgcn_mfma_f32_16x16x32_bf16(
                    ah[i], bh[j], acc[i][j], 0, 0, 0);
                acc[i][j] = __builtin_amdgcn_mfma_f32_16x16x32_bf16(
                    ah[i], bl[j], acc[i][j], 0, 0, 0);
                acc[i][j] = __builtin_amdgcn_mfma_f32_16x16x32_bf16(
                    al[i], bh[j], acc[i][j], 0, 0, 0);
            }
        __syncthreads();
    }

    const int cr = (lane >> 4) * 4, cc = lane & 15;
#pragma unroll
    for (int i = 0; i < 4; i++)
#pragma unroll
        for (int j = 0; j < 4; j++) {
            const int gj = j0 + wc + j * 16 + cc;
#pragma unroll
            for (int r = 0; r < 4; r++) {
                const int gi = i0 + wr + i * 16 + cr + r;
                Out[(long)gi * ldo + gj] = acc[i][j][r];
            }
        }
}

// ---------------------------------------------------------------------------
// Plain bf16 MFMA GEMM (back half), 128x128 tile, BK=32 (round-2 kernel).
//  OTRANS: vt[b][c][k'] transposed write;  OPERM: (b*1024+m*64+n)->(n,m,b)
// ---------------------------------------------------------------------------
template <bool OTRANS, bool BIAS, bool OPERM, bool OUT_BF16>
__global__ __launch_bounds__(256) void gemm_bf16(
    const short* __restrict__ A, const short* __restrict__ B,
    const float* __restrict__ bias, void* __restrict__ OutV,
    int Kdim, int lda, int ldb, int ldo, long sA, long sB, long sO)
{
    A += (long)blockIdx.z * sA;
    B += (long)blockIdx.z * sB;

    __shared__ __align__(16) short As[128][40];
    __shared__ __align__(16) short Bs[128][40];

    const int tid  = threadIdx.x;
    const int lane = tid & 63;
    const int wv   = tid >> 6;
    const int wr   = (wv >> 1) * 64;
    const int wc   = (wv & 1) * 64;
    const int i0 = blockIdx.x * 128, j0 = blockIdx.y * 128;

    floatx4 acc[4][4];
#pragma unroll
    for (int i = 0; i < 4; i++)
#pragma unroll
        for (int j = 0; j < 4; j++) acc[i][j] = {0.f, 0.f, 0.f, 0.f};

    const int srow = tid >> 2;
    const int sch  = (tid & 3) * 8;
    const int fr = lane & 15, fq = (lane >> 4) * 8;

    for (int k0 = 0; k0 < Kdim; k0 += 32) {
#pragma unroll
        for (int p = 0; p < 2; p++) {
            const int r = srow + p * 64;
            *(short8*)&As[r][sch] = *(const short8*)(A + (long)(i0 + r) * lda + k0 + sch);
            *(short8*)&Bs[r][sch] = *(const short8*)(B + (long)(j0 + r) * ldb + k0 + sch);
        }
        __syncthreads();
        short8 af[4], bf[4];
#pragma unroll
        for (int i = 0; i < 4; i++) af[i] = *(const short8*)&As[wr + i * 16 + fr][fq];
#pragma unroll
        for (int j = 0; j < 4; j++) bf[j] = *(const short8*)&Bs[wc + j * 16 + fr][fq];
#pragma unroll
        for (int i = 0; i < 4; i++)
#pragma unroll
            for (int j = 0; j < 4; j++)
                acc[i][j] = __builtin_amdgcn_mfma_f32_16x16x32_bf16(
                    af[i], bf[j], acc[i][j], 0, 0, 0);
        __syncthreads();
    }

    float* Of = nullptr; unsigned short* Ob = nullptr;
    if constexpr (OUT_BF16) Ob = (unsigned short*)OutV + (long)blockIdx.z * sO;
    else                    Of = (float*)OutV + (long)blockIdx.z * sO;
    const int cr = (lane >> 4) * 4, cc = lane & 15;
#pragma unroll
    for (int i = 0; i < 4; i++) {
#pragma unroll
        for (int j = 0; j < 4; j++) {
            const int gj = j0 + wc + j * 16 + cc;
            float bb = 0.0f;
            if constexpr (BIAS) bb = bias[gj];
#pragma unroll
            for (int r = 0; r < 4; r++) {
                const int gi = i0 + wr + i * 16 + cr + r;
                float v = acc[i][j][r] + bb;
                long idx;
                if constexpr (OTRANS)
                    idx = (long)(gi >> 8) * 131072 + (long)gj * 256 + (gi & 255);
                else if constexpr (OPERM)
                    idx = (long)((gi & 63) * 128 + ((gi >> 6) & 15) * 8 + (gi >> 10)) * ldo + gj;
                else
                    idx = (long)gi * ldo + gj;
                if constexpr (OUT_BF16) Ob[idx] = f2bf(v);
                else                    Of[idx] = v;
            }
        }
    }
}

// ---------------------------------------------------------------------------
// Per-row L2 normalize fp32 -> split bf16 (hi/lo).  One wave per 512-row.
// PERM: q rows (n*16+m)*8+b -> b*1024 + m*64 + n
// ---------------------------------------------------------------------------
template <bool PERM>
__global__ __launch_bounds__(256) void l2norm_split(
    const float* __restrict__ src,
    unsigned short* __restrict__ dh, unsigned short* __restrict__ dl)
{
    const int row  = blockIdx.x * 4 + (threadIdx.x >> 6);
    const int lane = threadIdx.x & 63;
    const float* s = src + (long)row * 512 + lane * 8;
    float x[8];
    *(float4*)&x[0] = *(const float4*)s;
    *(float4*)&x[4] = *(const float4*)(s + 4);
    float ss = 0.0f;
#pragma unroll
    for (int i = 0; i < 8; i++) ss = fmaf(x[i], x[i], ss);
#pragma unroll
    for (int off = 32; off; off >>= 1) ss += __shfl_xor(ss, off, 64);
    const float scale = 1.0f / fmaxf(sqrtf(ss), 1e-12f);
    long drow;
    if constexpr (PERM) {
        const int b = row & 7, m = (row >> 3) & 15, n = row >> 7;
        drow = (long)b * 1024 + m * 64 + n;
    } else {
        drow = row;
    }
    unsigned short hv[8], lv[8];
#pragma unroll
    for (int i = 0; i < 8; i++) {
        const float v = x[i] * scale;
        hv[i] = f2bf(v);
        lv[i] = f2bf(v - bf2f(hv[i]));
    }
    const long o = drow * 512 + lane * 8;
    *(ushort4*)(dh + o)     = *(ushort4*)&hv[0];
    *(ushort4*)(dh + o + 4) = *(ushort4*)&hv[4];
    *(ushort4*)(dl + o)     = *(ushort4*)&lv[0];
    *(ushort4*)(dl + o + 4) = *(ushort4*)&lv[4];
}

// ---------------------------------------------------------------------------
// Sinkhorn, dual-layout multiplicative form (round-2 kernel, unchanged).
// ---------------------------------------------------------------------------
__global__ __launch_bounds__(256) void sinkhorn2(
    const float* __restrict__ sim, float* __restrict__ score,
    unsigned short* __restrict__ Tt)
{
    __shared__ float lb[4][64];
    const int lane = threadIdx.x & 63;
    const int wv   = threadIdx.x >> 6;
    const int bk   = blockIdx.x * 4 + wv;
    const float* S = sim + (long)bk * 1024;

    float sv[16], K2[16];
#pragma unroll
    for (int m = 0; m < 16; m++) {
        sv[m] = S[m * 64 + lane];
        K2[m] = __expf((sv[m] - 1.0f) * 20.0f);
    }
    const int mB = lane & 15, nc = lane >> 4;
    float K1[16];
#pragma unroll
    for (int c4 = 0; c4 < 4; c4++) {
        float4 v = *(const float4*)(S + mB * 64 + nc * 16 + c4 * 4);
        K1[c4 * 4 + 0] = __expf((v.x - 1.0f) * 20.0f);
        K1[c4 * 4 + 1] = __expf((v.y - 1.0f) * 20.0f);
        K1[c4 * 4 + 2] = __expf((v.z - 1.0f) * 20.0f);
        K1[c4 * 4 + 3] = __expf((v.w - 1.0f) * 20.0f);
    }

    const float muP = 0.0625f + 1e-8f;
    const float nuP = 0.015625f + 1e-8f;
    float b = 1.0f, a = 0.0f;
    float bB[16];
#pragma unroll
    for (int j = 0; j < 16; j++) bB[j] = 1.0f;

#pragma unroll 1
    for (int it = 0; it < 100; it++) {
        float s0 = 0, s1 = 0, s2 = 0, s3 = 0;
#pragma unroll
        for (int j = 0; j < 4; j++) {
            s0 = fmaf(K1[j],      bB[j],      s0);
            s1 = fmaf(K1[4 + j],  bB[4 + j],  s1);
            s2 = fmaf(K1[8 + j],  bB[8 + j],  s2);
            s3 = fmaf(K1[12 + j], bB[12 + j], s3);
        }
        float s = (s0 + s1) + (s2 + s3);
        s += __shfl_xor(s, 16, 64);
        s += __shfl_xor(s, 32, 64);
        a = muP * fastrcp(s);
        float t0 = 0, t1 = 0, t2 = 0, t3 = 0;
#pragma unroll
        for (int m = 0; m < 4; m++) {
            t0 = fmaf(K2[m],      bcast(a, m),      t0);
            t1 = fmaf(K2[4 + m],  bcast(a, 4 + m),  t1);
            t2 = fmaf(K2[8 + m],  bcast(a, 8 + m),  t2);
            t3 = fmaf(K2[12 + m], bcast(a, 12 + m), t3);
        }
        b = nuP * fastrcp((t0 + t1) + (t2 + t3));
        lb[wv][lane] = b;
        const float* p = &lb[wv][nc * 16];
        float4 q0 = *(const float4*)(p + 0);
        float4 q1 = *(const float4*)(p + 4);
        float4 q2 = *(const float4*)(p + 8);
        float4 q3 = *(const float4*)(p + 12);
        bB[0] = q0.x; bB[1] = q0.y; bB[2]  = q0.z; bB[3]  = q0.w;
        bB[4] = q1.x; bB[5] = q1.y; bB[6]  = q1.z; bB[7]  = q1.w;
        bB[8] = q2.x; bB[9] = q2.y; bB[10] = q2.z; bB[11] = q2.w;
        bB[12] = q3.x; bB[13] = q3.y; bB[14] = q3.z; bB[15] = q3.w;
    }

    const long tb = (long)(bk >> 8) * 262144 + (bk & 255);
#pragma unroll
    for (int m = 0; m < 16; m++) {
        const float Tv = bcast(a, m) * K2[m] * b;
        score[(long)bk * 1024 + m * 64 + lane] = 1024.0f * sv[m] * Tv;
        Tt[tb + (long)(m * 64 + lane) * 256] = f2bf(Tv);
    }
}

__global__ __launch_bounds__(256) void cast_bf16(
    const float* __restrict__ src, unsigned short* __restrict__ dst, int n4)
{
    const int i = blockIdx.x * 256 + threadIdx.x;
    if (i < n4) {
        float4 v = ((const float4*)src)[i];
        ushort4 o;
        o.x = f2bf(v.x); o.y = f2bf(v.y); o.z = f2bf(v.z); o.w = f2bf(v.w);
        ((ushort4*)dst)[i] = o;
    }
}

// fp32 -> (hi, lo) bf16 pair; lo = bf16(x - f32(hi)) (x - hi is fp32-exact)
__global__ __launch_bounds__(256) void split_bf16(
    const float* __restrict__ src, unsigned short* __restrict__ dh,
    unsigned short* __restrict__ dl, int n4)
{
    const int i = blockIdx.x * 256 + threadIdx.x;
    if (i < n4) {
        float4 v = ((const float4*)src)[i];
        ushort4 h, l;
        h.x = f2bf(v.x); l.x = f2bf(v.x - bf2f(h.x));
        h.y = f2bf(v.y); l.y = f2bf(v.y - bf2f(h.y));
        h.z = f2bf(v.z); l.z = f2bf(v.z - bf2f(h.z));
        h.w = f2bf(v.w); l.w = f2bf(v.w - bf2f(h.w));
        ((ushort4*)dh)[i] = h;
        ((ushort4*)dl)[i] = l;
    }
}

extern "C" void kernel_launch(void* const* d_in, const int* in_sizes, int n_in,
                              void* d_out, int out_size, void* d_ws, size_t ws_size,
                              hipStream_t stream)
{
    (void)in_sizes; (void)n_in; (void)out_size; (void)ws_size;
    const float* xq = (const float*)d_in[0];
    const float* xk = (const float*)d_in[1];
    const float* xv = (const float*)d_in[2];
    const float* Wq = (const float*)d_in[3];
    const float* Wk = (const float*)d_in[4];
    const float* Wv = (const float*)d_in[5];
    const float* Wp = (const float*)d_in[6];
    const float* bp = (const float*)d_in[7];

    float* out_x     = (float*)d_out;           // (Nq,M,B,C) = 8192 x 512
    float* out_score = out_x + 8192L * 512;     // (B,K,M,Nq) = 2048 x 1024

    // workspace layout (45 MB; regions reused across lifetimes)
    char* W = (char*)d_ws;
    const long MB = 1 << 20;
    unsigned short* xq_h  = (unsigned short*)(W + 0);        // 8MB, dead after q-proj
    unsigned short* xq_l  = (unsigned short*)(W + 8 * MB);   // 8MB
    unsigned short* qh    = (unsigned short*)(W + 0);        // 8MB (reuses xq_h)
    unsigned short* ql    = (unsigned short*)(W + 8 * MB);   // 8MB (reuses xq_l)
    float*          qraw  = (float*)(W + 16 * MB);           // 16MB, dead after l2norm
    float*          simbuf= (float*)(W + 16 * MB);           //  8MB (reuses qraw)
    unsigned short* xpre  = (unsigned short*)(W + 24 * MB);  //  8MB (reuses qraw hi-half)
    float*          kraw  = (float*)(W + 32 * MB);           //  4MB, dead after l2norm k
    unsigned short* Tt    = (unsigned short*)(W + 32 * MB);  //  4MB (reuses kraw)
    unsigned short* xk_h  = (unsigned short*)(W + 36 * MB);  //  2MB, dead after k-proj
    unsigned short* xk_l  = (unsigned short*)(W + 38 * MB);  //  2MB
    unsigned short* kh    = (unsigned short*)(W + 36 * MB);  //  2MB (reuses xk_h)
    unsigned short* kl    = (unsigned short*)(W + 38 * MB);  //  2MB (reuses xk_l)
    unsigned short* xv_bf = (unsigned short*)(W + 40 * MB);  //  2MB
    unsigned short* vt    = (unsigned short*)(W + 42 * MB);  //  2MB [b][c][k']
    unsigned short* Wq_h  = (unsigned short*)(W + 44 * MB);            // 512KB each
    unsigned short* Wq_l  = (unsigned short*)(W + 44 * MB + 1 * 524288);
    unsigned short* Wk_h  = (unsigned short*)(W + 44 * MB + 2 * 524288);
    unsigned short* Wk_l  = (unsigned short*)(W + 44 * MB + 3 * 524288);
    unsigned short* Wv_bf = (unsigned short*)(W + 44 * MB + 4 * 524288);
    unsigned short* Wp_bf = (unsigned short*)(W + 44 * MB + 5 * 524288);

    const dim3 blk(256);

    // input splits / casts
    split_bf16<<<4096, blk, 0, stream>>>(xq, xq_h, xq_l, 1048576);
    split_bf16<<<1024, blk, 0, stream>>>(xk, xk_h, xk_l, 262144);
    split_bf16<<< 256, blk, 0, stream>>>(Wq, Wq_h, Wq_l, 65536);
    split_bf16<<< 256, blk, 0, stream>>>(Wk, Wk_h, Wk_l, 65536);
    cast_bf16 <<<1024, blk, 0, stream>>>(xv, xv_bf, 262144);
    cast_bf16 <<< 256, blk, 0, stream>>>(Wv, Wv_bf, 65536);
    cast_bf16 <<< 256, blk, 0, stream>>>(Wp, Wp_bf, 65536);

    // q/k projections (bf16x3 split MFMA -> fp32)
    gemm_split3<<<dim3(64, 4, 1), blk, 0, stream>>>(
        (const short*)xq_h, (const short*)xq_l, (const short*)Wq_h,
        (const short*)Wq_l, qraw, 512, 512, 512, 512, 0, 0, 0);
    gemm_split3<<<dim3(16, 4, 1), blk, 0, stream>>>(
        (const short*)xk_h, (const short*)xk_l, (const short*)Wk_h,
        (const short*)Wk_l, kraw, 512, 512, 512, 512, 0, 0, 0);

    // l2norm -> split bf16 (q permuted to [b][mn][c])
    l2norm_split<true ><<<2048, blk, 0, stream>>>(qraw, qh, ql);
    l2norm_split<false><<< 512, blk, 0, stream>>>(kraw, kh, kl);

    // v projection (plain bf16 MFMA), output transposed to vt[b][c][k']
    gemm_bf16<true, false, false, true><<<dim3(16, 4, 1), blk, 0, stream>>>(
        (const short*)xv_bf, (const short*)Wv_bf, nullptr, vt,
        512, 512, 512, 0, 0, 0, 0);

    // sim[b][k'][mn] (bf16x3 split MFMA -> fp32)
    gemm_split3<<<dim3(2, 8, 8), blk, 0, stream>>>(
        (const short*)kh, (const short*)kl, (const short*)qh, (const short*)ql,
        simbuf, 512, 512, 512, 1024, 131072, 524288, 262144);

    // Sinkhorn -> score (out) + T bf16 [b][mn][k']
    sinkhorn2<<<512, blk, 0, stream>>>(simbuf, out_score, Tt);

    // xpre[b][mn][c] = sum_k' T[b][mn][k'] * v[b][k'][c]   (bf16 MFMA)
    gemm_bf16<false, false, false, true><<<dim3(8, 4, 8), blk, 0, stream>>>(
        (const short*)Tt, (const short*)vt, nullptr, xpre,
        256, 256, 256, 512, 262144, 131072, 524288);

    // x = xpre @ Wp^T + bp, rows (b,mn)->(n,m,b)  (bf16 MFMA, fp32 out)
    gemm_bf16<false, true, true, false><<<dim3(64, 4, 1), blk, 0, stream>>>(
        (const short*)xpre, (const short*)Wp_bf, bp, out_x,
        512, 512, 512, 512, 0, 0, 0);
}